// Round 3
// baseline (407.710 us; speedup 1.0000x reference)
//
#include <hip/hip_runtime.h>

// ---------------------------------------------------------------------------
// GraphConvpoolMPNN: bs=16, S=17, N=256, F=64, MW=2 -> 256 windows, N1=512.
// Storage dtypes follow the REFERENCE (fp32) per the harness contract; the
// harness pre-rounds input values to the bf16 grid (hence bf16-gridpoint
// ref absmax + bf16 tolerance). A 3-way on-device detector classifies the
// w_map2 buffer (fp32-preround / fp32-raw / bf16-pairs) and canonicalizes
// inputs to bf16 workspace buffers. OUTPUT IS WRITTEN AS FP32.
// Pipeline:
//   k_detect / k_canon_x / k_canon_p : dtype detect + canonicalize to bf16
//   k_zero      : zero BN stats accumulators
//   k_y         : y[b,s] = x[b,s] @ Wmap^T + b   (272 slices, MFMA)
//   k_bn0_stats : weighted global mean/var of nf (slice weight 1/2/../2/1)
//   k_bnT       : xbT = BN0(y) transposed to [64f][256n] (B-operand layout)
//   k_pass<0>   : scores=lrelu(nf nf^T), softmax+mask in LDS, out1=adj@xb
//   k_pass<1>   : recompute scores, out2=adj@out1, fuse th0/th1 projection
//   k_bn1_stats : global mean/var of out_pre
//   k_final     : BN1 + leaky_relu + mean over 32 (l,m) windows -> fp32 out
// adj2@xb == adj@(adj@xb): the 512^3 adj@adj is never materialized.
// ---------------------------------------------------------------------------

typedef unsigned short u16;
typedef __bf16 bf16x8 __attribute__((ext_vector_type(8)));
typedef float f32x4 __attribute__((ext_vector_type(4)));
typedef unsigned int u32x4 __attribute__((ext_vector_type(4)));

#define MFMA16(a, b, c) __builtin_amdgcn_mfma_f32_16x16x32_bf16(a, b, c, 0, 0, 0)

#define BSZ 16
#define SNUM 17
#define FD 64
#define NB 256
#define N1 512
#define SL_ELEMS (256 * 64)              // 16384 per slice
#define Y_ELEMS (BSZ * SNUM * SL_ELEMS)  // 4456448

// canonical param buffer offsets (u16 elements)
#define WM_O 0
#define BM_O 4096
#define B0W_O 4160
#define B0B_O 4224
#define T0W_O 4288
#define T0B_O 8384
#define T1W_O 8448
#define T1B_O 12544
#define B1W_O 12608
#define B1B_O 12672
#define P_TOT 12736

__device__ __forceinline__ float bf2f(u16 u) {
    union { unsigned int i; float f; } v;
    v.i = ((unsigned int)u) << 16;
    return v.f;
}
__device__ __forceinline__ u16 f2bf(float f) {
    unsigned int u = __builtin_bit_cast(unsigned int, f);
    unsigned int r = (u + 0x7fffu + ((u >> 16) & 1u)) >> 16;
    return (u16)r;
}
__device__ __forceinline__ __bf16 f2bfv(float f) {
    u16 r = f2bf(f);
    return __builtin_bit_cast(__bf16, r);
}
__device__ __forceinline__ bf16x8 ld8g(const u16* p) {
    return __builtin_bit_cast(bf16x8, *reinterpret_cast<const u32x4*>(p));
}

// --------------------------- dtype detect ----------------------------------
// Inspect first 2048 u32s of w_map2 (in-bounds for both 8KB bf16 and 16KB
// fp32 buffers). Z = #(low16 == 0), B = #(bit14 set).
//   fp32 pre-rounded-to-bf16 : Z~2048, B~0
//   fp32 raw                 : Z~0,    B~1024 (random mantissa bit)
//   bf16 pairs (|v|<2)       : Z~0,    B~0    (bit14 = bf16 exp MSB = 0)
// flag=1 -> treat inputs as fp32.
__global__ void k_detect(const unsigned int* __restrict__ w, int* __restrict__ flag) {
    int z = 0, bc = 0;
    for (int i = threadIdx.x; i < 2048; i += 64) {
        const unsigned int v = w[i];
        z += ((v & 0xffffu) == 0u);
        bc += (v >> 14) & 1;
    }
    for (int o = 32; o; o >>= 1) {
        z += __shfl_down(z, o);
        bc += __shfl_down(bc, o);
    }
    if (threadIdx.x == 0) *flag = (z > 1024 || bc > 256) ? 1 : 0;
}

// --------------------------- canonicalize x --------------------------------
__global__ __launch_bounds__(256) void k_canon_x(const void* __restrict__ src,
                                                 const int* __restrict__ flag,
                                                 u16* __restrict__ xc) {
    const int i8 = blockIdx.x * 256 + threadIdx.x;  // 557056 chunks of 8
    if (*flag) {
        const f32x4* s = (const f32x4*)src;
        f32x4 a = s[2 * i8], b = s[2 * i8 + 1];
        union { u16 u[8]; u32x4 v; } pk;
#pragma unroll
        for (int j = 0; j < 4; j++) { pk.u[j] = f2bf(a[j]); pk.u[4 + j] = f2bf(b[j]); }
        *reinterpret_cast<u32x4*>(xc + i8 * 8) = pk.v;
    } else {
        *reinterpret_cast<u32x4*>(xc + i8 * 8) = ((const u32x4*)src)[i8];
    }
}

// --------------------------- canonicalize params ---------------------------
__global__ __launch_bounds__(256) void k_canon_p(
    const void* p0, const void* p1, const void* p2, const void* p3,
    const void* p4, const void* p5, const void* p6, const void* p7,
    const void* p8, const void* p9, const int* __restrict__ flag,
    u16* __restrict__ pc) {
    const int i = blockIdx.x * 256 + threadIdx.x;
    if (i >= P_TOT) return;
    const void* src;
    int si;
    if (i < BM_O)        { src = p0; si = i; }
    else if (i < B0W_O)  { src = p1; si = i - BM_O; }
    else if (i < B0B_O)  { src = p2; si = i - B0W_O; }
    else if (i < T0W_O)  { src = p3; si = i - B0B_O; }
    else if (i < T0B_O)  { src = p4; si = i - T0W_O; }
    else if (i < T1W_O)  { src = p5; si = i - T0B_O; }
    else if (i < T1B_O)  { src = p6; si = i - T1W_O; }
    else if (i < B1W_O)  { src = p7; si = i - T1B_O; }
    else if (i < B1B_O)  { src = p8; si = i - B1W_O; }
    else                 { src = p9; si = i - B1B_O; }
    pc[i] = (*flag) ? f2bf(((const float*)src)[si]) : ((const u16*)src)[si];
}

// --------------------------- zero stats ------------------------------------
__global__ void k_zero(float* stats) { stats[threadIdx.x] = 0.f; }

// --------------------------- y = x @ W^T + b -------------------------------
__global__ __launch_bounds__(256) void k_y(const u16* __restrict__ x,
                                           const u16* __restrict__ pc,
                                           u16* __restrict__ y) {
    const int slice = blockIdx.x;  // 272
    const u16* xs = x + (size_t)slice * SL_ELEMS;
    u16* ys = y + (size_t)slice * SL_ELEMS;
    const int tid = threadIdx.x, wave = tid >> 6, lane = tid & 63;
    const int quad = lane >> 4, l16 = lane & 15;
    const u16* wm = pc + WM_O;

    f32x4 acc[4][4];
#pragma unroll
    for (int i = 0; i < 4; i++)
#pragma unroll
        for (int j = 0; j < 4; j++) acc[i][j] = (f32x4){0.f, 0.f, 0.f, 0.f};

    bf16x8 bfr[4][2];
#pragma unroll
    for (int nt = 0; nt < 4; nt++)
#pragma unroll
        for (int kh = 0; kh < 2; kh++)
            bfr[nt][kh] = ld8g(wm + (nt * 16 + l16) * 64 + kh * 32 + quad * 8);

#pragma unroll
    for (int mt = 0; mt < 4; mt++) {
        const int row = wave * 64 + mt * 16 + l16;
        bf16x8 a0 = ld8g(xs + row * 64 + quad * 8);
        bf16x8 a1 = ld8g(xs + row * 64 + 32 + quad * 8);
#pragma unroll
        for (int nt = 0; nt < 4; nt++) {
            acc[mt][nt] = MFMA16(a0, bfr[nt][0], acc[mt][nt]);
            acc[mt][nt] = MFMA16(a1, bfr[nt][1], acc[mt][nt]);
        }
    }
#pragma unroll
    for (int nt = 0; nt < 4; nt++) {
        const int col = nt * 16 + l16;
        const float bias = bf2f(pc[BM_O + col]);
#pragma unroll
        for (int mt = 0; mt < 4; mt++)
#pragma unroll
            for (int r = 0; r < 4; r++) {
                const int row = wave * 64 + mt * 16 + quad * 4 + r;
                ys[row * 64 + col] = f2bf(acc[mt][nt][r] + bias);
            }
    }
}

// --------------------------- BN0 statistics --------------------------------
__global__ __launch_bounds__(256) void k_bn0_stats(const u16* __restrict__ y,
                                                   float* __restrict__ stats) {
    const int tid = threadIdx.x;
    const int gt = blockIdx.x * 256 + tid;
    float s1 = 0.f, s2 = 0.f;
    for (int k = 0; k < Y_ELEMS / 32768; k++) {
        const int idx = gt + k * 32768;
        const int s = (idx / SL_ELEMS) % SNUM;
        const float w = (s == 0 || s == SNUM - 1) ? 1.f : 2.f;
        const float v = bf2f(y[idx]);
        s1 += w * v;
        s2 += w * v * v;
    }
    __shared__ float a1[256], a2[256];
    a1[tid] = s1;
    a2[tid] = s2;
    __syncthreads();
    if (tid < 64) {
        float t1 = a1[tid] + a1[tid + 64] + a1[tid + 128] + a1[tid + 192];
        float t2 = a2[tid] + a2[tid + 64] + a2[tid + 128] + a2[tid + 192];
        atomicAdd(&stats[tid], t1);
        atomicAdd(&stats[64 + tid], t2);
    }
}

// --------------------------- xbT = BN0(y) transposed -----------------------
__global__ __launch_bounds__(256) void k_bnT(const u16* __restrict__ y,
                                             const float* __restrict__ stats,
                                             const u16* __restrict__ pc,
                                             u16* __restrict__ xbT) {
    const int slice = blockIdx.x >> 2, chunk = blockIdx.x & 3;
    const int tid = threadIdx.x;
    const int f = tid & 63;
    const float inv = 1.f / 131072.f;
    const float mu = stats[f] * inv;
    const float var = fmaxf(stats[64 + f] * inv - mu * mu, 0.f);
    const float rs = rsqrtf(var + 1e-5f);
    const float scale = rs * bf2f(pc[B0W_O + f]);
    const float shift = bf2f(pc[B0B_O + f]) - mu * scale;

    __shared__ u16 tile[64][72];
    const size_t base = (size_t)slice * SL_ELEMS + (size_t)chunk * 4096;
#pragma unroll
    for (int it = 0; it < 16; it++) {
        const int idx = it * 256 + tid;
        const int nl = idx >> 6;
        tile[nl][f] = f2bf(bf2f(y[base + idx]) * scale + shift);
    }
    __syncthreads();
    u16* xt = xbT + (size_t)slice * SL_ELEMS + chunk * 64;
#pragma unroll
    for (int it = 0; it < 2; it++) {
        const int cid = it * 256 + tid;
        const int f2 = cid >> 3, nd0 = (cid & 7) * 8;
        union { u16 u[8]; u32x4 v; } pk;
#pragma unroll
        for (int j = 0; j < 8; j++) pk.u[j] = tile[nd0 + j][f2];
        *reinterpret_cast<u32x4*>(xt + (size_t)f2 * 256 + nd0) = pk.v;
    }
}

// --------------------------- main fused passes -----------------------------
template <int PASS>
__global__ __launch_bounds__(256) void k_pass(
    const u16* __restrict__ y, const u16* __restrict__ bsrc,
    const u16* __restrict__ eyesrc, const float* __restrict__ stats,
    const u16* __restrict__ pc, u16* __restrict__ o_bf, u16* __restrict__ oT,
    float* __restrict__ out_pre) {
    __shared__ float sc[16][516];
    __shared__ u16 arows[16 * 72];
    __shared__ u16 stg[64 * 72];

    const int bid = blockIdx.x;
    const int xcd = bid & 7, idx = bid >> 3;
    const int p = xcd * 32 + (idx >> 5);
    const int rblk = idx & 31;
    const int b = p >> 4, l = p & 15;
    const int hi = rblk >> 4;
    const int i0 = rblk * 16;
    const int rbase = i0 & 255;
    const int tid = threadIdx.x, wave = tid >> 6, lane = tid & 63;
    const int quad = lane >> 4, l16 = lane & 15;
    const u16* yrows = y + (size_t)(b * SNUM + l + hi) * SL_ELEMS;

    // phase 1: stage the 16 nf rows
    if (tid < 128) {
        const int row = tid >> 3, f0 = (tid & 7) * 8;
        *reinterpret_cast<u32x4*>(&arows[row * 72 + f0]) =
            *reinterpret_cast<const u32x4*>(yrows + (rbase + row) * 64 + f0);
    }
    __syncthreads();
    bf16x8 af0 = *reinterpret_cast<const bf16x8*>(&arows[l16 * 72 + quad * 8]);
    bf16x8 af1 = *reinterpret_cast<const bf16x8*>(&arows[l16 * 72 + 32 + quad * 8]);

    // phase 2: scores = leaky_relu(nf nf^T), diag -> -1e9
    for (int c = 0; c < 8; c++) {
        const int hc = c >> 2, cb = (c * 64) & 255;
        const u16* ycol = y + (size_t)(b * SNUM + l + hc) * SL_ELEMS;
        __syncthreads();
#pragma unroll
        for (int it = 0; it < 2; it++) {
            const int row = it * 32 + (tid >> 3), f0 = (tid & 7) * 8;
            *reinterpret_cast<u32x4*>(&stg[row * 72 + f0]) =
                *reinterpret_cast<const u32x4*>(ycol + (cb + row) * 64 + f0);
        }
        __syncthreads();
        bf16x8 b0 = *reinterpret_cast<const bf16x8*>(&stg[(wave * 16 + l16) * 72 + quad * 8]);
        bf16x8 b1 = *reinterpret_cast<const bf16x8*>(&stg[(wave * 16 + l16) * 72 + 32 + quad * 8]);
        f32x4 z = (f32x4){0.f, 0.f, 0.f, 0.f};
        z = MFMA16(af0, b0, z);
        z = MFMA16(af1, b1, z);
#pragma unroll
        for (int r = 0; r < 4; r++) {
            const int rl = quad * 4 + r;
            const int ig = i0 + rl;
            const int jg = c * 64 + wave * 16 + l16;
            float s = z[r];
            s = s > 0.f ? s : 0.01f * s;
            s = fminf(fmaxf(s, -1e9f), 1e5f);  // scrub NaN/Inf -> finite
            if (ig == jg) s = -1e9f;           // exp underflows to 0, as ref
            sc[rl][jg] = s;
        }
    }
    __syncthreads();

    // phase 3: softmax + decay mask, in place
    {
        const int row = tid >> 4, sub = tid & 15;
        float mx = -1e30f;
        for (int k = 0; k < 32; k++) mx = fmaxf(mx, sc[row][sub + k * 16]);
        mx = fmaxf(mx, __shfl_xor(mx, 1));
        mx = fmaxf(mx, __shfl_xor(mx, 2));
        mx = fmaxf(mx, __shfl_xor(mx, 4));
        mx = fmaxf(mx, __shfl_xor(mx, 8));
        float sm = 0.f;
        for (int k = 0; k < 32; k++) sm += __expf(sc[row][sub + k * 16] - mx);
        sm += __shfl_xor(sm, 1);
        sm += __shfl_xor(sm, 2);
        sm += __shfl_xor(sm, 4);
        sm += __shfl_xor(sm, 8);
        const float inv = 1.f / sm;
        for (int k = 0; k < 32; k++) {
            const int col = sub + k * 16;
            const float mf = ((col >> 8) == hi) ? 1.f : 0.7f;
            sc[row][col] = __expf(sc[row][col] - mx) * inv * mf;
        }
    }

    // phase 4: oacc = P @ (xb | out1)
    f32x4 oacc = (f32x4){0.f, 0.f, 0.f, 0.f};
    for (int c = 0; c < 8; c++) {
        const u16* bsl;
        int cb;
        if (PASS == 0) {
            const int hc = c >> 2;
            cb = (c * 64) & 255;
            bsl = bsrc + (size_t)(b * SNUM + l + hc) * SL_ELEMS;
        } else {
            cb = c * 64;
            bsl = bsrc + (size_t)p * (64 * 512);
        }
        __syncthreads();
#pragma unroll
        for (int it = 0; it < 2; it++) {
            const int fr = it * 32 + (tid >> 3), nd0 = (tid & 7) * 8;
            *reinterpret_cast<u32x4*>(&stg[fr * 72 + nd0]) =
                *reinterpret_cast<const u32x4*>(bsl + (size_t)fr * (PASS == 0 ? 256 : 512) + cb + nd0);
        }
        __syncthreads();
        const float* sp0 = &sc[l16][c * 64 + quad * 8];
        const float* sp1 = sp0 + 32;
        bf16x8 pa0, pa1;
#pragma unroll
        for (int j = 0; j < 8; j++) {
            pa0[j] = f2bfv(sp0[j]);
            pa1[j] = f2bfv(sp1[j]);
        }
        bf16x8 xb0 = *reinterpret_cast<const bf16x8*>(&stg[(wave * 16 + l16) * 72 + quad * 8]);
        bf16x8 xb1 = *reinterpret_cast<const bf16x8*>(&stg[(wave * 16 + l16) * 72 + 32 + quad * 8]);
        oacc = MFMA16(pa0, xb0, oacc);
        oacc = MFMA16(pa1, xb1, oacc);
    }
    __syncthreads();  // phase-4 LDS reads done before arows reuse

    // epilogue: add identity term, stash block as bf16 in LDS
    {
        const int col = wave * 16 + l16;
        float ev[4];
        if (PASS == 0) {
            // eye = BN0(y) computed on the fly (fp32, matches ref's fp32 xb)
            const float inv = 1.f / 131072.f;
            const float mu = stats[col] * inv;
            const float var = fmaxf(stats[64 + col] * inv - mu * mu, 0.f);
            const float rs = rsqrtf(var + 1e-5f);
            const float scale = rs * bf2f(pc[B0W_O + col]);
            const float shift = bf2f(pc[B0B_O + col]) - mu * scale;
            const u16* yr = yrows + (size_t)rbase * 64;
#pragma unroll
            for (int r = 0; r < 4; r++)
                ev[r] = bf2f(yr[(quad * 4 + r) * 64 + col]) * scale + shift;
        } else {
            const u16* er = eyesrc + (size_t)p * (N1 * FD) + (size_t)i0 * 64;
#pragma unroll
            for (int r = 0; r < 4; r++) ev[r] = bf2f(er[(quad * 4 + r) * 64 + col]);
        }
#pragma unroll
        for (int r = 0; r < 4; r++) {
            const int rl = quad * 4 + r;
            arows[rl * 72 + col] = f2bf(oacc[r] + ev[r]);
        }
    }
    __syncthreads();

    if (PASS == 0) {
        if (tid < 128) {  // out1, row-major
            const int row = tid >> 3, f0 = (tid & 7) * 8;
            *reinterpret_cast<u32x4*>(o_bf + (size_t)p * (N1 * FD) + (size_t)(i0 + row) * 64 + f0) =
                *reinterpret_cast<const u32x4*>(&arows[row * 72 + f0]);
        }
        if (tid < 128) {  // out1T [64f][512n]
            const int f = tid >> 1, part = tid & 1;
            union { u16 u[8]; u32x4 v; } pk;
#pragma unroll
            for (int j = 0; j < 8; j++) pk.u[j] = arows[(part * 8 + j) * 72 + f];
            *reinterpret_cast<u32x4*>(oT + (size_t)p * (FD * N1) + (size_t)f * 512 + i0 + part * 8) = pk.v;
        }
    } else {
        // fused projection: out_pre = out1@th0^T + out2@th1^T + b0 + b1
        const int col = wave * 16 + l16;
        const float bias = bf2f(pc[T0B_O + col]) + bf2f(pc[T1B_O + col]);
        f32x4 pacc = (f32x4){bias, bias, bias, bias};
        const u16* o1r = eyesrc + (size_t)p * (N1 * FD) + (size_t)i0 * 64;
        bf16x8 a10 = ld8g(o1r + l16 * 64 + quad * 8);
        bf16x8 a11 = ld8g(o1r + l16 * 64 + 32 + quad * 8);
        bf16x8 a20 = *reinterpret_cast<const bf16x8*>(&arows[l16 * 72 + quad * 8]);
        bf16x8 a21 = *reinterpret_cast<const bf16x8*>(&arows[l16 * 72 + 32 + quad * 8]);
        bf16x8 w00 = ld8g(pc + T0W_O + col * 64 + quad * 8);
        bf16x8 w01 = ld8g(pc + T0W_O + col * 64 + 32 + quad * 8);
        bf16x8 w10 = ld8g(pc + T1W_O + col * 64 + quad * 8);
        bf16x8 w11 = ld8g(pc + T1W_O + col * 64 + 32 + quad * 8);
        pacc = MFMA16(a10, w00, pacc);
        pacc = MFMA16(a11, w01, pacc);
        pacc = MFMA16(a20, w10, pacc);
        pacc = MFMA16(a21, w11, pacc);
        float* op = out_pre + (size_t)p * (N1 * FD);
#pragma unroll
        for (int r = 0; r < 4; r++) {
            const int rl = quad * 4 + r;
            op[(size_t)(i0 + rl) * 64 + col] = pacc[r];
        }
    }
}

// --------------------------- BN1 statistics --------------------------------
__global__ __launch_bounds__(256) void k_bn1_stats(const float* __restrict__ op,
                                                   float* __restrict__ stats) {
    const int tid = threadIdx.x;
    const size_t base = (size_t)blockIdx.x * 32768 + tid;
    float s1 = 0.f, s2 = 0.f;
    for (int k = 0; k < 128; k++) {
        const float v = op[base + (size_t)k * 256];
        s1 += v;
        s2 += v * v;
    }
    __shared__ float a1[256], a2[256];
    a1[tid] = s1;
    a2[tid] = s2;
    __syncthreads();
    if (tid < 64) {
        float t1 = a1[tid] + a1[tid + 64] + a1[tid + 128] + a1[tid + 192];
        float t2 = a2[tid] + a2[tid + 64] + a2[tid + 128] + a2[tid + 192];
        atomicAdd(&stats[128 + tid], t1);
        atomicAdd(&stats[192 + tid], t2);
    }
}

// --------------------------- BN1 + lrelu + pooling -> fp32 out -------------
__global__ __launch_bounds__(256) void k_final(const float* __restrict__ op,
                                               const float* __restrict__ stats,
                                               const u16* __restrict__ pc,
                                               float* __restrict__ out) {
    const int o = blockIdx.x * 256 + threadIdx.x;
    const int f = o & 63, n = (o >> 6) & 255, b = o >> 14;
    const float inv = 1.f / 131072.f;
    const float mu = stats[128 + f] * inv;
    const float var = fmaxf(stats[192 + f] * inv - mu * mu, 0.f);
    const float rs = rsqrtf(var + 1e-5f);
    const float scale = rs * bf2f(pc[B1W_O + f]);
    const float shift = bf2f(pc[B1B_O + f]) - mu * scale;
    float acc = 0.f;
    for (int l = 0; l < 16; l++) {
        const size_t pb = (size_t)(b * 16 + l) * N1 * FD;
#pragma unroll
        for (int m = 0; m < 2; m++) {
            float v = op[pb + (size_t)(m * 256 + n) * 64 + f];
            v = v * scale + shift;
            acc += (v > 0.f ? v : 0.01f * v);
        }
    }
    out[o] = acc * (1.f / 32.f);
}

// ---------------------------------------------------------------------------
extern "C" void kernel_launch(void* const* d_in, const int* in_sizes, int n_in,
                              void* d_out, int out_size, void* d_ws, size_t ws_size,
                              hipStream_t stream) {
    char* ws = (char*)d_ws;
    size_t off = 0;
    auto alloc = [&](size_t bytes) { void* pp = ws + off; off += (bytes + 255) & ~(size_t)255; return pp; };
    u16* xc = (u16*)alloc((size_t)Y_ELEMS * 2);
    u16* y = (u16*)alloc((size_t)Y_ELEMS * 2);
    u16* xbT = (u16*)alloc((size_t)Y_ELEMS * 2);
    u16* out1 = (u16*)alloc((size_t)NB * N1 * FD * 2);
    u16* out1T = (u16*)alloc((size_t)NB * N1 * FD * 2);
    float* opre = (float*)alloc((size_t)NB * N1 * FD * 4);
    u16* pc = (u16*)alloc(P_TOT * 2);
    float* stats = (float*)alloc(256 * 4);
    int* flag = (int*)alloc(256);
    float* out = (float*)d_out;

    k_detect<<<1, 64, 0, stream>>>((const unsigned int*)d_in[1], flag);
    k_canon_x<<<Y_ELEMS / 8 / 256, 256, 0, stream>>>(d_in[0], flag, xc);
    k_canon_p<<<50, 256, 0, stream>>>(d_in[1], d_in[2], d_in[3], d_in[4], d_in[5],
                                      d_in[6], d_in[7], d_in[8], d_in[9], d_in[10],
                                      flag, pc);
    k_zero<<<1, 256, 0, stream>>>(stats);
    k_y<<<BSZ * SNUM, 256, 0, stream>>>(xc, pc, y);
    k_bn0_stats<<<128, 256, 0, stream>>>(y, stats);
    k_bnT<<<BSZ * SNUM * 4, 256, 0, stream>>>(y, stats, pc, xbT);
    k_pass<0><<<8192, 256, 0, stream>>>(y, xbT, out1, stats, pc, out1, out1T, opre);
    k_pass<1><<<8192, 256, 0, stream>>>(y, out1T, out1, stats, pc, out1, out1T, opre);
    k_bn1_stats<<<256, 256, 0, stream>>>(opre, stats);
    k_final<<<1024, 256, 0, stream>>>(opre, stats, pc, out);
}

// Round 5
// 255.717 us; speedup vs baseline: 1.5944x; 1.5944x over previous
//
#include <hip/hip_runtime.h>

// ---------------------------------------------------------------------------
// GraphConvpoolMPNN fused rewrite. bs=16,S=17,N=256,F=64,MW=2 -> 256 windows,
// N1=512. One workgroup per window; nf slab (512x64 bf16) + xbT/out1T slab
// (64x512 bf16) resident in LDS (XOR-swizzled); softmax without max-
// subtraction (scores bounded; clamped); P transposed C->A layout via
// per-wave LDS scratch (in-order DS, no barriers). adj2@xb == adj@(adj@xb).
// Pipeline: detect -> canon_p -> zero -> k_y (x@W^T + fused BN0 stats)
//           -> k_mega (scores/softmax/mask/2 hops/projection + BN1 stats)
//           -> k_final (BN1 + lrelu + window mean) -> fp32 out.
// ---------------------------------------------------------------------------

typedef unsigned short u16;
typedef __bf16 bf16x8 __attribute__((ext_vector_type(8)));
typedef float f32x4 __attribute__((ext_vector_type(4)));
typedef unsigned int u32x4 __attribute__((ext_vector_type(4)));

#define MFMA16(a, b, c) __builtin_amdgcn_mfma_f32_16x16x32_bf16(a, b, c, 0, 0, 0)

#define BSZ 16
#define SNUM 17
#define FD 64
#define NB 256
#define N1 512
#define SL_ELEMS 16384
#define Y_ELEMS (BSZ * SNUM * SL_ELEMS)

// canonical param buffer offsets (u16 elements)
#define WM_O 0
#define BM_O 4096
#define B0W_O 4160
#define B0B_O 4224
#define T0W_O 4288
#define T0B_O 8384
#define T1W_O 8448
#define T1B_O 12544
#define B1W_O 12608
#define B1B_O 12672
#define P_TOT 12736

// k_mega LDS map (u16 units): slab1 [512][64] XOR, slab2 [64][512] XOR,
// red 128 floats, scr 8 waves x (16 rows x 40)
#define SLAB2_O 32768
#define RED_O 65536
#define SCR_O 65792
#define LDS_BYTES ((SCR_O + 8 * 640) * 2)  // 141,824 B

__device__ __forceinline__ float bf2f(u16 u) {
    union { unsigned int i; float f; } v;
    v.i = ((unsigned int)u) << 16;
    return v.f;
}
__device__ __forceinline__ u16 f2bu(float f) {  // RNE via HW cvt
    __bf16 h = (__bf16)f;
    return __builtin_bit_cast(u16, h);
}
__device__ __forceinline__ u16 f2bf(float f) {  // manual RNE (canon path)
    unsigned int u = __builtin_bit_cast(unsigned int, f);
    unsigned int r = (u + 0x7fffu + ((u >> 16) & 1u)) >> 16;
    return (u16)r;
}
__device__ __forceinline__ bf16x8 ld8g(const u16* p) {
    return __builtin_bit_cast(bf16x8, *reinterpret_cast<const u32x4*>(p));
}

// --------------------------- dtype detect ----------------------------------
__global__ void k_detect(const unsigned int* __restrict__ w, int* __restrict__ flag) {
    int z = 0, bc = 0;
    for (int i = threadIdx.x; i < 2048; i += 64) {
        const unsigned int v = w[i];
        z += ((v & 0xffffu) == 0u);
        bc += (v >> 14) & 1;
    }
    for (int o = 32; o; o >>= 1) {
        z += __shfl_down(z, o);
        bc += __shfl_down(bc, o);
    }
    if (threadIdx.x == 0) *flag = (z > 1024 || bc > 256) ? 1 : 0;
}

// --------------------------- canonicalize params ---------------------------
__global__ __launch_bounds__(256) void k_canon_p(
    const void* p0, const void* p1, const void* p2, const void* p3,
    const void* p4, const void* p5, const void* p6, const void* p7,
    const void* p8, const void* p9, const int* __restrict__ flag,
    u16* __restrict__ pc) {
    const int i = blockIdx.x * 256 + threadIdx.x;
    if (i >= P_TOT) return;
    const void* src;
    int si;
    if (i < BM_O)        { src = p0; si = i; }
    else if (i < B0W_O)  { src = p1; si = i - BM_O; }
    else if (i < B0B_O)  { src = p2; si = i - B0W_O; }
    else if (i < T0W_O)  { src = p3; si = i - B0B_O; }
    else if (i < T0B_O)  { src = p4; si = i - T0W_O; }
    else if (i < T1W_O)  { src = p5; si = i - T0B_O; }
    else if (i < T1B_O)  { src = p6; si = i - T1W_O; }
    else if (i < B1W_O)  { src = p7; si = i - T1B_O; }
    else if (i < B1B_O)  { src = p8; si = i - B1W_O; }
    else                 { src = p9; si = i - B1B_O; }
    pc[i] = (*flag) ? f2bf(((const float*)src)[si]) : ((const u16*)src)[si];
}

// --------------------------- zero stats ------------------------------------
__global__ void k_zero(float* stats) { stats[threadIdx.x] = 0.f; }

// ------------------- y = x @ W^T + b  (+ fused BN0 stats) ------------------
__global__ __launch_bounds__(256) void k_y(const void* __restrict__ xv,
                                           const int* __restrict__ flag,
                                           const u16* __restrict__ pc,
                                           u16* __restrict__ y,
                                           float* __restrict__ gstats) {
    const int slice = blockIdx.x;  // 272
    const int tid = threadIdx.x, wave = tid >> 6, lane = tid & 63;
    const int quad = lane >> 4, l16 = lane & 15;
    __shared__ float red[128];
    if (tid < 128) red[tid] = 0.f;
    const int isf32 = *flag;

    f32x4 acc[4][4];
#pragma unroll
    for (int i = 0; i < 4; i++)
#pragma unroll
        for (int j = 0; j < 4; j++) acc[i][j] = (f32x4){0.f, 0.f, 0.f, 0.f};

    bf16x8 bfr[4][2];
#pragma unroll
    for (int nt = 0; nt < 4; nt++)
#pragma unroll
        for (int kh = 0; kh < 2; kh++)
            bfr[nt][kh] = ld8g(pc + WM_O + (nt * 16 + l16) * 64 + kh * 32 + quad * 8);

    const float* xf = (const float*)xv + (size_t)slice * SL_ELEMS;
    const u16* xh = (const u16*)xv + (size_t)slice * SL_ELEMS;

#pragma unroll
    for (int mt = 0; mt < 4; mt++) {
        const int row = wave * 64 + mt * 16 + l16;
        bf16x8 a0, a1;
        if (isf32) {
            const float* r0 = xf + row * 64 + quad * 8;
            f32x4 v0 = *(const f32x4*)r0;
            f32x4 v1 = *(const f32x4*)(r0 + 4);
            f32x4 v2 = *(const f32x4*)(r0 + 32);
            f32x4 v3 = *(const f32x4*)(r0 + 36);
#pragma unroll
            for (int j = 0; j < 4; j++) {
                a0[j] = (__bf16)v0[j]; a0[4 + j] = (__bf16)v1[j];
                a1[j] = (__bf16)v2[j]; a1[4 + j] = (__bf16)v3[j];
            }
        } else {
            a0 = ld8g(xh + row * 64 + quad * 8);
            a1 = ld8g(xh + row * 64 + 32 + quad * 8);
        }
#pragma unroll
        for (int nt = 0; nt < 4; nt++)
            acc[mt][nt] = MFMA16(a1, bfr[nt][1], MFMA16(a0, bfr[nt][0], acc[mt][nt]));
    }

    u16* ys = y + (size_t)slice * SL_ELEMS;
    float s1[4] = {0.f, 0.f, 0.f, 0.f}, s2[4] = {0.f, 0.f, 0.f, 0.f};
#pragma unroll
    for (int nt = 0; nt < 4; nt++) {
        const int col = nt * 16 + l16;
        const float bias = bf2f(pc[BM_O + col]);
#pragma unroll
        for (int mt = 0; mt < 4; mt++)
#pragma unroll
            for (int r = 0; r < 4; r++) {
                const int row = wave * 64 + mt * 16 + quad * 4 + r;
                const float v = acc[mt][nt][r] + bias;
                ys[row * 64 + col] = f2bu(v);
                s1[nt] += v;
                s2[nt] += v * v;
            }
        s1[nt] += __shfl_xor(s1[nt], 16); s1[nt] += __shfl_xor(s1[nt], 32);
        s2[nt] += __shfl_xor(s2[nt], 16); s2[nt] += __shfl_xor(s2[nt], 32);
    }
    __syncthreads();
    if (quad == 0) {
#pragma unroll
        for (int nt = 0; nt < 4; nt++) {
            atomicAdd(&red[nt * 16 + l16], s1[nt]);
            atomicAdd(&red[64 + nt * 16 + l16], s2[nt]);
        }
    }
    __syncthreads();
    const int s = slice % SNUM;
    const float wgt = (s == 0 || s == SNUM - 1) ? 1.f : 2.f;
    if (tid < 128) atomicAdd(&gstats[tid], red[tid] * wgt);
}

// --------------------------- the fused window kernel -----------------------
__global__ __launch_bounds__(512, 2) void k_mega(
    const u16* __restrict__ y, float* __restrict__ stats,
    const u16* __restrict__ pc, u16* __restrict__ opre) {
    extern __shared__ u16 lds[];
    u16* slab1 = lds;                       // [n 0..511][g 0..7] XOR(n&7)
    u16* slab2 = lds + SLAB2_O;             // [f 0..63][gn 0..63] XOR(f)
    float* red = (float*)(lds + RED_O);     // 128 floats for BN1 partials
    const int tid = threadIdx.x, w = tid >> 6, lane = tid & 63;
    const int quad = lane >> 4, l16 = lane & 15;
    u16* scr = lds + SCR_O + w * 640;       // 16 rows x 40 u16, per wave
    const int p = blockIdx.x, b = p >> 4, l = p & 15;
    const f32x4 ZERO4 = (f32x4){0.f, 0.f, 0.f, 0.f};

    if (tid < 128) red[tid] = 0.f;

    // BN0 affine constants
    const float cinv = 1.f / 131072.f;
    const int fme = tid & 63;
    float mu0 = stats[fme] * cinv;
    float vr0 = fmaxf(stats[64 + fme] * cinv - mu0 * mu0, 0.f);
    const float scale_f = rsqrtf(vr0 + 1e-5f) * bf2f(pc[B0W_O + fme]);
    const float shift_f = bf2f(pc[B0B_O + fme]) - mu0 * scale_f;
    float escl[4], eshf[4];
#pragma unroll
    for (int ft = 0; ft < 4; ft++) {
        const int col = ft * 16 + l16;
        float m = stats[col] * cinv;
        float v = fmaxf(stats[64 + col] * cinv - m * m, 0.f);
        escl[ft] = rsqrtf(v + 1e-5f) * bf2f(pc[B0W_O + col]);
        eshf[ft] = bf2f(pc[B0B_O + col]) - m * escl[ft];
    }

    // stage nf slab (two consecutive slices = contiguous 512x64)
    const u16* ybase = y + (size_t)(b * SNUM + l) * SL_ELEMS;
#pragma unroll
    for (int i = 0; i < 8; i++) {
        const int gid = i * 512 + tid, n = gid >> 3, g = gid & 7;
        *(u32x4*)(slab1 + n * 64 + ((g ^ (n & 7)) << 3)) =
            *(const u32x4*)(ybase + n * 64 + g * 8);
    }
    __syncthreads();

    // build slab2 = xbT = BN0(nf) transposed, bf16
#pragma unroll
    for (int i = 0; i < 8; i++) {
        const int gn = (tid >> 6) + i * 8;
        union { u16 u[8]; u32x4 v; } pk;
#pragma unroll
        for (int j = 0; j < 8; j++) {
            const int n = gn * 8 + j;
            const u16 raw = slab1[n * 64 + (((fme >> 3) ^ (n & 7)) << 3) + (fme & 7)];
            pk.u[j] = f2bu(bf2f(raw) * scale_f + shift_f);
        }
        *(u32x4*)(slab2 + fme * 512 + ((gn ^ fme) << 3)) = pk.v;
    }
    __syncthreads();

    // hoist nf A-frags for this wave's 64 rows (4 subtiles of 16)
    bf16x8 a[4][2];
#pragma unroll
    for (int st = 0; st < 4; st++)
#pragma unroll
        for (int h = 0; h < 2; h++) {
            const int row = w * 64 + st * 16 + l16;
            a[st][h] = *(const bf16x8*)(slab1 + row * 64 + (((h * 4 + quad) ^ (row & 7)) << 3));
        }

    for (int pass = 0; pass < 2; pass++) {
        f32x4 oacc[4][4];
        f32x4 lsum[4];
#pragma unroll
        for (int st = 0; st < 4; st++) {
            lsum[st] = ZERO4;
#pragma unroll
            for (int ft = 0; ft < 4; ft++) oacc[st][ft] = ZERO4;
        }

        for (int c = 0; c < 8; c++) {
            const float mf = ((w >= 4) == (c >= 4)) ? 1.f : 0.7f;
            bf16x8 bs[4][2], bv[2][4];
#pragma unroll
            for (int jt = 0; jt < 4; jt++)
#pragma unroll
                for (int h = 0; h < 2; h++) {
                    const int rj = c * 64 + jt * 16 + l16;
                    bs[jt][h] = *(const bf16x8*)(slab1 + rj * 64 + (((h * 4 + quad) ^ (rj & 7)) << 3));
                }
#pragma unroll
            for (int h = 0; h < 2; h++)
#pragma unroll
                for (int ft = 0; ft < 4; ft++) {
                    const int f = ft * 16 + l16, gn = c * 8 + h * 4 + quad;
                    bv[h][ft] = *(const bf16x8*)(slab2 + f * 512 + ((gn ^ f) << 3));
                }
#pragma unroll
            for (int st = 0; st < 4; st++) {
                f32x4 S[4];
#pragma unroll
                for (int jt = 0; jt < 4; jt++) {
                    f32x4 t = MFMA16(a[st][0], bs[jt][0], ZERO4);
                    S[jt] = MFMA16(a[st][1], bs[jt][1], t);
                }
                u16 pb[4][4];
#pragma unroll
                for (int jt = 0; jt < 4; jt++)
#pragma unroll
                    for (int r = 0; r < 4; r++) {
                        const float s = S[jt][r];
                        // leaky_relu folded into exp2 domain
                        const float m2 = s > 0.f ? 1.44269504f : 0.0144269504f;
                        float pv = exp2f(fminf(s * m2, 86.f));
                        if (jt == st && c == w && l16 == quad * 4 + r) pv = 0.f;  // diag
                        lsum[st][r] += pv;
                        pb[jt][r] = f2bu(pv * mf);
                    }
#pragma unroll
                for (int h = 0; h < 2; h++) {
#pragma unroll
                    for (int jtl = 0; jtl < 2; jtl++)
#pragma unroll
                        for (int r = 0; r < 4; r++)
                            scr[(quad * 4 + r) * 40 + jtl * 16 + l16] = pb[2 * h + jtl][r];
                    const bf16x8 pa = *(const bf16x8*)(scr + l16 * 40 + quad * 8);
#pragma unroll
                    for (int ft = 0; ft < 4; ft++)
                        oacc[st][ft] = MFMA16(pa, bv[h][ft], oacc[st][ft]);
                }
            }
        }
        // softmax denominators (per row, butterfly over the 16 col-lanes)
#pragma unroll
        for (int st = 0; st < 4; st++)
#pragma unroll
            for (int r = 0; r < 4; r++) {
                lsum[st][r] += __shfl_xor(lsum[st][r], 1);
                lsum[st][r] += __shfl_xor(lsum[st][r], 2);
                lsum[st][r] += __shfl_xor(lsum[st][r], 4);
                lsum[st][r] += __shfl_xor(lsum[st][r], 8);
            }

        if (pass == 0) {
            // out1 = P@xb / l + xb(own row)
#pragma unroll
            for (int st = 0; st < 4; st++) {
                f32x4 inv;
#pragma unroll
                for (int r = 0; r < 4; r++) inv[r] = __builtin_amdgcn_rcpf(lsum[st][r]);
#pragma unroll
                for (int ft = 0; ft < 4; ft++)
#pragma unroll
                    for (int r = 0; r < 4; r++) {
                        const int i = w * 64 + st * 16 + quad * 4 + r;
                        const int col = ft * 16 + l16;
                        const float xbv =
                            bf2f(slab1[i * 64 + (((col >> 3) ^ (i & 7)) << 3) + (col & 7)]) * escl[ft] + eshf[ft];
                        oacc[st][ft][r] = oacc[st][ft][r] * inv[r] + xbv;
                    }
            }
            __syncthreads();  // all waves done reading xbT
#pragma unroll
            for (int st = 0; st < 4; st++)
#pragma unroll
                for (int ft = 0; ft < 4; ft++)
#pragma unroll
                    for (int r = 0; r < 4; r++) {
                        const int i = w * 64 + st * 16 + quad * 4 + r;
                        const int f = ft * 16 + l16;
                        slab2[f * 512 + (((i >> 3) ^ f) << 3) + (i & 7)] = f2bu(oacc[st][ft][r]);
                    }
            __syncthreads();  // out1T visible for pass 1
        } else {
            // out2 = P@out1 / l + out1(own); fused projection + BN1 partials
            float s1a[4] = {0.f, 0.f, 0.f, 0.f}, s2a[4] = {0.f, 0.f, 0.f, 0.f};
            bf16x8 w0f[2][4], w1f[2][4];
#pragma unroll
            for (int h = 0; h < 2; h++)
#pragma unroll
                for (int ot = 0; ot < 4; ot++) {
                    const int o = ot * 16 + l16;
                    w0f[h][ot] = ld8g(pc + T0W_O + o * 64 + h * 32 + quad * 8);
                    w1f[h][ot] = ld8g(pc + T1W_O + o * 64 + h * 32 + quad * 8);
                }
#pragma unroll
            for (int st = 0; st < 4; st++) {
                f32x4 inv;
#pragma unroll
                for (int r = 0; r < 4; r++) inv[r] = __builtin_amdgcn_rcpf(lsum[st][r]);
#pragma unroll
                for (int ft = 0; ft < 4; ft++)
#pragma unroll
                    for (int r = 0; r < 4; r++) {
                        const int i = w * 64 + st * 16 + quad * 4 + r;
                        const int col = ft * 16 + l16;
                        const float o1 = bf2f(slab2[col * 512 + (((i >> 3) ^ col) << 3) + (i & 7)]);
                        oacc[st][ft][r] = oacc[st][ft][r] * inv[r] + o1;
                    }
                // a1 = out1 A-frag (from out1T slab, scalar gather)
                bf16x8 a1[2], a2[2];
                const int irow = w * 64 + st * 16 + l16;
#pragma unroll
                for (int h = 0; h < 2; h++)
#pragma unroll
                    for (int j = 0; j < 8; j++) {
                        const int f = h * 32 + quad * 8 + j;
                        const u16 raw = slab2[f * 512 + (((irow >> 3) ^ f) << 3) + (irow & 7)];
                        a1[h][j] = __builtin_bit_cast(__bf16, raw);
                    }
                // a2 = out2 A-frag via per-wave scratch
#pragma unroll
                for (int h = 0; h < 2; h++) {
#pragma unroll
                    for (int ftl = 0; ftl < 2; ftl++)
#pragma unroll
                        for (int r = 0; r < 4; r++)
                            scr[(quad * 4 + r) * 40 + ftl * 16 + l16] = f2bu(oacc[st][2 * h + ftl][r]);
                    a2[h] = *(const bf16x8*)(scr + l16 * 40 + quad * 8);
                }
                f32x4 pacc[4];
#pragma unroll
                for (int ot = 0; ot < 4; ot++) {
                    const int o = ot * 16 + l16;
                    const float bias = bf2f(pc[T0B_O + o]) + bf2f(pc[T1B_O + o]);
                    pacc[ot] = (f32x4){bias, bias, bias, bias};
                }
#pragma unroll
                for (int h = 0; h < 2; h++)
#pragma unroll
                    for (int ot = 0; ot < 4; ot++) {
                        pacc[ot] = MFMA16(a1[h], w0f[h][ot], pacc[ot]);
                        pacc[ot] = MFMA16(a2[h], w1f[h][ot], pacc[ot]);
                    }
#pragma unroll
                for (int ot = 0; ot < 4; ot++)
#pragma unroll
                    for (int r = 0; r < 4; r++) {
                        const int i = w * 64 + st * 16 + quad * 4 + r;
                        const int o = ot * 16 + l16;
                        const float v = pacc[ot][r];
                        s1a[ot] += v;
                        s2a[ot] += v * v;
                        opre[(size_t)p * (N1 * FD) + (size_t)i * 64 + o] = f2bu(v);
                    }
            }
#pragma unroll
            for (int ot = 0; ot < 4; ot++) {
                s1a[ot] += __shfl_xor(s1a[ot], 16); s1a[ot] += __shfl_xor(s1a[ot], 32);
                s2a[ot] += __shfl_xor(s2a[ot], 16); s2a[ot] += __shfl_xor(s2a[ot], 32);
            }
            if (quad == 0) {
#pragma unroll
                for (int ot = 0; ot < 4; ot++) {
                    atomicAdd(&red[ot * 16 + l16], s1a[ot]);
                    atomicAdd(&red[64 + ot * 16 + l16], s2a[ot]);
                }
            }
            __syncthreads();
            if (tid < 128) atomicAdd(&stats[128 + tid], red[tid]);
        }
    }
}

// --------------------------- BN1 + lrelu + pooling -> fp32 out -------------
__global__ __launch_bounds__(256) void k_final(const u16* __restrict__ op,
                                               const float* __restrict__ stats,
                                               const u16* __restrict__ pc,
                                               float* __restrict__ out) {
    const int o = blockIdx.x * 256 + threadIdx.x;
    const int f = o & 63, n = (o >> 6) & 255, b = o >> 14;
    const float inv = 1.f / 131072.f;
    const float mu = stats[128 + f] * inv;
    const float var = fmaxf(stats[192 + f] * inv - mu * mu, 0.f);
    const float rs = rsqrtf(var + 1e-5f);
    const float scale = rs * bf2f(pc[B1W_O + f]);
    const float shift = bf2f(pc[B1B_O + f]) - mu * scale;
    float acc = 0.f;
    for (int l = 0; l < 16; l++) {
        const size_t pb = (size_t)(b * 16 + l) * N1 * FD;
#pragma unroll
        for (int m = 0; m < 2; m++) {
            float v = bf2f(op[pb + (size_t)(m * 256 + n) * 64 + f]);
            v = v * scale + shift;
            acc += (v > 0.f ? v : 0.01f * v);
        }
    }
    out[o] = acc * (1.f / 32.f);
}

// ---------------------------------------------------------------------------
extern "C" void kernel_launch(void* const* d_in, const int* in_sizes, int n_in,
                              void* d_out, int out_size, void* d_ws, size_t ws_size,
                              hipStream_t stream) {
    char* ws = (char*)d_ws;
    size_t off = 0;
    auto alloc = [&](size_t bytes) { void* pp = ws + off; off += (bytes + 255) & ~(size_t)255; return pp; };
    u16* y = (u16*)alloc((size_t)Y_ELEMS * 2);
    u16* opre = (u16*)alloc((size_t)NB * N1 * FD * 2);
    u16* pc = (u16*)alloc(P_TOT * 2);
    float* stats = (float*)alloc(256 * 4);
    int* flag = (int*)alloc(256);
    float* out = (float*)d_out;

    k_detect<<<1, 64, 0, stream>>>((const unsigned int*)d_in[1], flag);
    k_canon_p<<<50, 256, 0, stream>>>(d_in[1], d_in[2], d_in[3], d_in[4], d_in[5],
                                      d_in[6], d_in[7], d_in[8], d_in[9], d_in[10],
                                      flag, pc);
    k_zero<<<1, 256, 0, stream>>>(stats);
    k_y<<<BSZ * SNUM, 256, 0, stream>>>(d_in[0], flag, pc, y, stats);
    k_mega<<<NB, 512, LDS_BYTES, stream>>>(y, stats, pc, opre);
    k_final<<<1024, 256, 0, stream>>>(opre, stats, pc, out);
}

// Round 6
// 249.951 us; speedup vs baseline: 1.6312x; 1.0231x over previous
//
#include <hip/hip_runtime.h>

// ---------------------------------------------------------------------------
// GraphConvpoolMPNN fused rewrite. bs=16,S=17,N=256,F=64,MW=2 -> 256 windows,
// N1=512. One workgroup per window; nf slab (512x64 bf16) + xbT/out1T slab
// (64x512 bf16) resident in LDS (XOR-swizzled). adj2@xb == adj@(adj@xb).
// R6: __launch_bounds__(512) [no min-wave bound] — LDS already caps the CU at
// 1 WG, so the R5 (512,2) bound only caused ~200 MB/dispatch of VGPR spill
// (FETCH 88 MB / WRITE 153 MB vs 17/17 algorithmic). Prep fused to 1 kernel.
// Pipeline: k_prep (detect+canon+zero) -> k_y (x@W^T + BN0 stats)
//           -> k_mega (scores/softmax/mask/2 hops/projection + BN1 stats)
//           -> k_final (BN1 + lrelu + window mean) -> fp32 out.
// ---------------------------------------------------------------------------

typedef unsigned short u16;
typedef __bf16 bf16x8 __attribute__((ext_vector_type(8)));
typedef float f32x4 __attribute__((ext_vector_type(4)));
typedef unsigned int u32x4 __attribute__((ext_vector_type(4)));

#define MFMA16(a, b, c) __builtin_amdgcn_mfma_f32_16x16x32_bf16(a, b, c, 0, 0, 0)

#define BSZ 16
#define SNUM 17
#define FD 64
#define NB 256
#define N1 512
#define SL_ELEMS 16384
#define Y_ELEMS (BSZ * SNUM * SL_ELEMS)

// canonical param buffer offsets (u16 elements)
#define WM_O 0
#define BM_O 4096
#define B0W_O 4160
#define B0B_O 4224
#define T0W_O 4288
#define T0B_O 8384
#define T1W_O 8448
#define T1B_O 12544
#define B1W_O 12608
#define B1B_O 12672
#define P_TOT 12736

// k_mega LDS map (u16 units): slab1 [512][64] XOR, slab2 [64][512] XOR,
// red 128 floats, scr 8 waves x (16 rows x 40)
#define SLAB2_O 32768
#define RED_O 65536
#define SCR_O 65792
#define LDS_BYTES ((SCR_O + 8 * 640) * 2)  // 141,824 B -> 1 WG/CU

__device__ __forceinline__ float bf2f(u16 u) {
    union { unsigned int i; float f; } v;
    v.i = ((unsigned int)u) << 16;
    return v.f;
}
__device__ __forceinline__ u16 f2bu(float f) {  // RNE via HW cvt
    __bf16 h = (__bf16)f;
    return __builtin_bit_cast(u16, h);
}
__device__ __forceinline__ u16 f2bf(float f) {  // manual RNE (canon path)
    unsigned int u = __builtin_bit_cast(unsigned int, f);
    unsigned int r = (u + 0x7fffu + ((u >> 16) & 1u)) >> 16;
    return (u16)r;
}
__device__ __forceinline__ bf16x8 ld8g(const u16* p) {
    return __builtin_bit_cast(bf16x8, *reinterpret_cast<const u32x4*>(p));
}

// ---------------- prep: dtype detect + canon params + zero stats -----------
// Each wave independently recomputes the dtype flag from the first 2048 u32s
// of w_map2 (8 KB, L2-hot): Z = #(low16==0), B = #(bit14 set).
//   fp32 pre-rounded-to-bf16: Z~2048,B~0 | fp32 raw: Z~0,B~1024 | bf16: Z~0,B~0
__global__ __launch_bounds__(256) void k_prep(
    const void* p0, const void* p1, const void* p2, const void* p3,
    const void* p4, const void* p5, const void* p6, const void* p7,
    const void* p8, const void* p9, int* __restrict__ flagOut,
    u16* __restrict__ pc, float* __restrict__ stats) {
    const int tid = threadIdx.x, lane = tid & 63;
    int z = 0, bc = 0;
    const unsigned int* w = (const unsigned int*)p0;
    for (int i = lane; i < 2048; i += 64) {
        const unsigned int v = w[i];
        z += ((v & 0xffffu) == 0u);
        bc += (v >> 14) & 1;
    }
#pragma unroll
    for (int o = 1; o < 64; o <<= 1) {
        z += __shfl_xor(z, o);
        bc += __shfl_xor(bc, o);
    }
    const int flag = (z > 1024 || bc > 256) ? 1 : 0;
    if (blockIdx.x == 0) {
        if (tid == 0) *flagOut = flag;
        if (tid < 256) stats[tid] = 0.f;
    }
    const int i = blockIdx.x * 256 + tid;
    if (i >= P_TOT) return;
    const void* src;
    int si;
    if (i < BM_O)        { src = p0; si = i; }
    else if (i < B0W_O)  { src = p1; si = i - BM_O; }
    else if (i < B0B_O)  { src = p2; si = i - B0W_O; }
    else if (i < T0W_O)  { src = p3; si = i - B0B_O; }
    else if (i < T0B_O)  { src = p4; si = i - T0W_O; }
    else if (i < T1W_O)  { src = p5; si = i - T0B_O; }
    else if (i < T1B_O)  { src = p6; si = i - T1W_O; }
    else if (i < B1W_O)  { src = p7; si = i - T1B_O; }
    else if (i < B1B_O)  { src = p8; si = i - B1W_O; }
    else                 { src = p9; si = i - B1B_O; }
    pc[i] = flag ? f2bf(((const float*)src)[si]) : ((const u16*)src)[si];
}

// ------------------- y = x @ W^T + b  (+ fused BN0 stats) ------------------
__global__ __launch_bounds__(256) void k_y(const void* __restrict__ xv,
                                           const int* __restrict__ flag,
                                           const u16* __restrict__ pc,
                                           u16* __restrict__ y,
                                           float* __restrict__ gstats) {
    const int slice = blockIdx.x;  // 272
    const int tid = threadIdx.x, wave = tid >> 6, lane = tid & 63;
    const int quad = lane >> 4, l16 = lane & 15;
    __shared__ float red[128];
    if (tid < 128) red[tid] = 0.f;
    const int isf32 = *flag;

    f32x4 acc[4][4];
#pragma unroll
    for (int i = 0; i < 4; i++)
#pragma unroll
        for (int j = 0; j < 4; j++) acc[i][j] = (f32x4){0.f, 0.f, 0.f, 0.f};

    bf16x8 bfr[4][2];
#pragma unroll
    for (int nt = 0; nt < 4; nt++)
#pragma unroll
        for (int kh = 0; kh < 2; kh++)
            bfr[nt][kh] = ld8g(pc + WM_O + (nt * 16 + l16) * 64 + kh * 32 + quad * 8);

    const float* xf = (const float*)xv + (size_t)slice * SL_ELEMS;
    const u16* xh = (const u16*)xv + (size_t)slice * SL_ELEMS;

#pragma unroll
    for (int mt = 0; mt < 4; mt++) {
        const int row = wave * 64 + mt * 16 + l16;
        bf16x8 a0, a1;
        if (isf32) {
            const float* r0 = xf + row * 64 + quad * 8;
            f32x4 v0 = *(const f32x4*)r0;
            f32x4 v1 = *(const f32x4*)(r0 + 4);
            f32x4 v2 = *(const f32x4*)(r0 + 32);
            f32x4 v3 = *(const f32x4*)(r0 + 36);
#pragma unroll
            for (int j = 0; j < 4; j++) {
                a0[j] = (__bf16)v0[j]; a0[4 + j] = (__bf16)v1[j];
                a1[j] = (__bf16)v2[j]; a1[4 + j] = (__bf16)v3[j];
            }
        } else {
            a0 = ld8g(xh + row * 64 + quad * 8);
            a1 = ld8g(xh + row * 64 + 32 + quad * 8);
        }
#pragma unroll
        for (int nt = 0; nt < 4; nt++)
            acc[mt][nt] = MFMA16(a1, bfr[nt][1], MFMA16(a0, bfr[nt][0], acc[mt][nt]));
    }

    u16* ys = y + (size_t)slice * SL_ELEMS;
    float s1[4] = {0.f, 0.f, 0.f, 0.f}, s2[4] = {0.f, 0.f, 0.f, 0.f};
#pragma unroll
    for (int nt = 0; nt < 4; nt++) {
        const int col = nt * 16 + l16;
        const float bias = bf2f(pc[BM_O + col]);
#pragma unroll
        for (int mt = 0; mt < 4; mt++)
#pragma unroll
            for (int r = 0; r < 4; r++) {
                const int row = wave * 64 + mt * 16 + quad * 4 + r;
                const float v = acc[mt][nt][r] + bias;
                ys[row * 64 + col] = f2bu(v);
                s1[nt] += v;
                s2[nt] += v * v;
            }
        s1[nt] += __shfl_xor(s1[nt], 16); s1[nt] += __shfl_xor(s1[nt], 32);
        s2[nt] += __shfl_xor(s2[nt], 16); s2[nt] += __shfl_xor(s2[nt], 32);
    }
    __syncthreads();
    if (quad == 0) {
#pragma unroll
        for (int nt = 0; nt < 4; nt++) {
            atomicAdd(&red[nt * 16 + l16], s1[nt]);
            atomicAdd(&red[64 + nt * 16 + l16], s2[nt]);
        }
    }
    __syncthreads();
    const int s = slice % SNUM;
    const float wgt = (s == 0 || s == SNUM - 1) ? 1.f : 2.f;
    if (tid < 128) atomicAdd(&gstats[tid], red[tid] * wgt);
}

// --------------------------- the fused window kernel -----------------------
// No min-wave bound: LDS (141.8 KB) already caps residency at 1 WG/CU, so the
// register allocator may use the full unified VGPR/AGPR file (live set ~220).
__global__ __launch_bounds__(512) void k_mega(
    const u16* __restrict__ y, float* __restrict__ stats,
    const u16* __restrict__ pc, u16* __restrict__ opre) {
    extern __shared__ u16 lds[];
    u16* slab1 = lds;                       // [n 0..511][g 0..7] XOR(n&7)
    u16* slab2 = lds + SLAB2_O;             // [f 0..63][gn 0..63] XOR(f)
    float* red = (float*)(lds + RED_O);     // 128 floats for BN1 partials
    const int tid = threadIdx.x, w = tid >> 6, lane = tid & 63;
    const int quad = lane >> 4, l16 = lane & 15;
    u16* scr = lds + SCR_O + w * 640;       // 16 rows x 40 u16, per wave
    const int p = blockIdx.x, b = p >> 4, l = p & 15;
    const f32x4 ZERO4 = (f32x4){0.f, 0.f, 0.f, 0.f};

    if (tid < 128) red[tid] = 0.f;

    // BN0 affine constants
    const float cinv = 1.f / 131072.f;
    const int fme = tid & 63;
    float mu0 = stats[fme] * cinv;
    float vr0 = fmaxf(stats[64 + fme] * cinv - mu0 * mu0, 0.f);
    const float scale_f = rsqrtf(vr0 + 1e-5f) * bf2f(pc[B0W_O + fme]);
    const float shift_f = bf2f(pc[B0B_O + fme]) - mu0 * scale_f;
    float escl[4], eshf[4];
#pragma unroll
    for (int ft = 0; ft < 4; ft++) {
        const int col = ft * 16 + l16;
        float m = stats[col] * cinv;
        float v = fmaxf(stats[64 + col] * cinv - m * m, 0.f);
        escl[ft] = rsqrtf(v + 1e-5f) * bf2f(pc[B0W_O + col]);
        eshf[ft] = bf2f(pc[B0B_O + col]) - m * escl[ft];
    }

    // stage nf slab (two consecutive slices = contiguous 512x64)
    const u16* ybase = y + (size_t)(b * SNUM + l) * SL_ELEMS;
#pragma unroll
    for (int i = 0; i < 8; i++) {
        const int gid = i * 512 + tid, n = gid >> 3, g = gid & 7;
        *(u32x4*)(slab1 + n * 64 + ((g ^ (n & 7)) << 3)) =
            *(const u32x4*)(ybase + n * 64 + g * 8);
    }
    __syncthreads();

    // build slab2 = xbT = BN0(nf) transposed, bf16
#pragma unroll
    for (int i = 0; i < 8; i++) {
        const int gn = (tid >> 6) + i * 8;
        union { u16 u[8]; u32x4 v; } pk;
#pragma unroll
        for (int j = 0; j < 8; j++) {
            const int n = gn * 8 + j;
            const u16 raw = slab1[n * 64 + (((fme >> 3) ^ (n & 7)) << 3) + (fme & 7)];
            pk.u[j] = f2bu(bf2f(raw) * scale_f + shift_f);
        }
        *(u32x4*)(slab2 + fme * 512 + ((gn ^ fme) << 3)) = pk.v;
    }
    __syncthreads();

    // hoist nf A-frags for this wave's 64 rows (4 subtiles of 16)
    bf16x8 a[4][2];
#pragma unroll
    for (int st = 0; st < 4; st++)
#pragma unroll
        for (int h = 0; h < 2; h++) {
            const int row = w * 64 + st * 16 + l16;
            a[st][h] = *(const bf16x8*)(slab1 + row * 64 + (((h * 4 + quad) ^ (row & 7)) << 3));
        }

    for (int pass = 0; pass < 2; pass++) {
        f32x4 oacc[4][4];
        f32x4 lsum[4];
#pragma unroll
        for (int st = 0; st < 4; st++) {
            lsum[st] = ZERO4;
#pragma unroll
            for (int ft = 0; ft < 4; ft++) oacc[st][ft] = ZERO4;
        }

        for (int c = 0; c < 8; c++) {
            const float mf = ((w >= 4) == (c >= 4)) ? 1.f : 0.7f;
            bf16x8 bs[4][2], bv[2][4];
#pragma unroll
            for (int jt = 0; jt < 4; jt++)
#pragma unroll
                for (int h = 0; h < 2; h++) {
                    const int rj = c * 64 + jt * 16 + l16;
                    bs[jt][h] = *(const bf16x8*)(slab1 + rj * 64 + (((h * 4 + quad) ^ (rj & 7)) << 3));
                }
#pragma unroll
            for (int h = 0; h < 2; h++)
#pragma unroll
                for (int ft = 0; ft < 4; ft++) {
                    const int f = ft * 16 + l16, gn = c * 8 + h * 4 + quad;
                    bv[h][ft] = *(const bf16x8*)(slab2 + f * 512 + ((gn ^ f) << 3));
                }
#pragma unroll
            for (int st = 0; st < 4; st++) {
                f32x4 S[4];
#pragma unroll
                for (int jt = 0; jt < 4; jt++) {
                    f32x4 t = MFMA16(a[st][0], bs[jt][0], ZERO4);
                    S[jt] = MFMA16(a[st][1], bs[jt][1], t);
                }
                u16 pb[4][4];
#pragma unroll
                for (int jt = 0; jt < 4; jt++)
#pragma unroll
                    for (int r = 0; r < 4; r++) {
                        const float s = S[jt][r];
                        // leaky_relu folded into exp2 domain
                        const float m2 = s > 0.f ? 1.44269504f : 0.0144269504f;
                        float pv = exp2f(fminf(s * m2, 86.f));
                        if (jt == st && c == w && l16 == quad * 4 + r) pv = 0.f;  // diag
                        lsum[st][r] += pv;
                        pb[jt][r] = f2bu(pv * mf);
                    }
#pragma unroll
                for (int h = 0; h < 2; h++) {
#pragma unroll
                    for (int jtl = 0; jtl < 2; jtl++)
#pragma unroll
                        for (int r = 0; r < 4; r++)
                            scr[(quad * 4 + r) * 40 + jtl * 16 + l16] = pb[2 * h + jtl][r];
                    const bf16x8 pa = *(const bf16x8*)(scr + l16 * 40 + quad * 8);
#pragma unroll
                    for (int ft = 0; ft < 4; ft++)
                        oacc[st][ft] = MFMA16(pa, bv[h][ft], oacc[st][ft]);
                }
            }
        }
        // softmax denominators (per row, butterfly over the 16 col-lanes)
#pragma unroll
        for (int st = 0; st < 4; st++)
#pragma unroll
            for (int r = 0; r < 4; r++) {
                lsum[st][r] += __shfl_xor(lsum[st][r], 1);
                lsum[st][r] += __shfl_xor(lsum[st][r], 2);
                lsum[st][r] += __shfl_xor(lsum[st][r], 4);
                lsum[st][r] += __shfl_xor(lsum[st][r], 8);
            }

        if (pass == 0) {
            // out1 = P@xb / l + xb(own row)
#pragma unroll
            for (int st = 0; st < 4; st++) {
                f32x4 inv;
#pragma unroll
                for (int r = 0; r < 4; r++) inv[r] = __builtin_amdgcn_rcpf(lsum[st][r]);
#pragma unroll
                for (int ft = 0; ft < 4; ft++)
#pragma unroll
                    for (int r = 0; r < 4; r++) {
                        const int i = w * 64 + st * 16 + quad * 4 + r;
                        const int col = ft * 16 + l16;
                        const float xbv =
                            bf2f(slab1[i * 64 + (((col >> 3) ^ (i & 7)) << 3) + (col & 7)]) * escl[ft] + eshf[ft];
                        oacc[st][ft][r] = oacc[st][ft][r] * inv[r] + xbv;
                    }
            }
            __syncthreads();  // all waves done reading xbT
#pragma unroll
            for (int st = 0; st < 4; st++)
#pragma unroll
                for (int ft = 0; ft < 4; ft++)
#pragma unroll
                    for (int r = 0; r < 4; r++) {
                        const int i = w * 64 + st * 16 + quad * 4 + r;
                        const int f = ft * 16 + l16;
                        slab2[f * 512 + (((i >> 3) ^ f) << 3) + (i & 7)] = f2bu(oacc[st][ft][r]);
                    }
            __syncthreads();  // out1T visible for pass 1
        } else {
            // out2 = P@out1 / l + out1(own); fused projection + BN1 partials
            float s1a[4] = {0.f, 0.f, 0.f, 0.f}, s2a[4] = {0.f, 0.f, 0.f, 0.f};
            bf16x8 w0f[2][4], w1f[2][4];
#pragma unroll
            for (int h = 0; h < 2; h++)
#pragma unroll
                for (int ot = 0; ot < 4; ot++) {
                    const int o = ot * 16 + l16;
                    w0f[h][ot] = ld8g(pc + T0W_O + o * 64 + h * 32 + quad * 8);
                    w1f[h][ot] = ld8g(pc + T1W_O + o * 64 + h * 32 + quad * 8);
                }
#pragma unroll
            for (int st = 0; st < 4; st++) {
                f32x4 inv;
#pragma unroll
                for (int r = 0; r < 4; r++) inv[r] = __builtin_amdgcn_rcpf(lsum[st][r]);
#pragma unroll
                for (int ft = 0; ft < 4; ft++)
#pragma unroll
                    for (int r = 0; r < 4; r++) {
                        const int i = w * 64 + st * 16 + quad * 4 + r;
                        const int col = ft * 16 + l16;
                        const float o1 = bf2f(slab2[col * 512 + (((i >> 3) ^ col) << 3) + (i & 7)]);
                        oacc[st][ft][r] = oacc[st][ft][r] * inv[r] + o1;
                    }
                // a1 = out1 A-frag (from out1T slab, scalar gather)
                bf16x8 a1[2], a2[2];
                const int irow = w * 64 + st * 16 + l16;
#pragma unroll
                for (int h = 0; h < 2; h++)
#pragma unroll
                    for (int j = 0; j < 8; j++) {
                        const int f = h * 32 + quad * 8 + j;
                        const u16 raw = slab2[f * 512 + (((irow >> 3) ^ f) << 3) + (irow & 7)];
                        a1[h][j] = __builtin_bit_cast(__bf16, raw);
                    }
                // a2 = out2 A-frag via per-wave scratch
#pragma unroll
                for (int h = 0; h < 2; h++) {
#pragma unroll
                    for (int ftl = 0; ftl < 2; ftl++)
#pragma unroll
                        for (int r = 0; r < 4; r++)
                            scr[(quad * 4 + r) * 40 + ftl * 16 + l16] = f2bu(oacc[st][2 * h + ftl][r]);
                    a2[h] = *(const bf16x8*)(scr + l16 * 40 + quad * 8);
                }
                f32x4 pacc[4];
#pragma unroll
                for (int ot = 0; ot < 4; ot++) {
                    const int o = ot * 16 + l16;
                    const float bias = bf2f(pc[T0B_O + o]) + bf2f(pc[T1B_O + o]);
                    pacc[ot] = (f32x4){bias, bias, bias, bias};
                }
#pragma unroll
                for (int h = 0; h < 2; h++)
#pragma unroll
                    for (int ot = 0; ot < 4; ot++) {
                        pacc[ot] = MFMA16(a1[h], w0f[h][ot], pacc[ot]);
                        pacc[ot] = MFMA16(a2[h], w1f[h][ot], pacc[ot]);
                    }
#pragma unroll
                for (int ot = 0; ot < 4; ot++)
#pragma unroll
                    for (int r = 0; r < 4; r++) {
                        const int i = w * 64 + st * 16 + quad * 4 + r;
                        const int o = ot * 16 + l16;
                        const float v = pacc[ot][r];
                        s1a[ot] += v;
                        s2a[ot] += v * v;
                        opre[(size_t)p * (N1 * FD) + (size_t)i * 64 + o] = f2bu(v);
                    }
            }
#pragma unroll
            for (int ot = 0; ot < 4; ot++) {
                s1a[ot] += __shfl_xor(s1a[ot], 16); s1a[ot] += __shfl_xor(s1a[ot], 32);
                s2a[ot] += __shfl_xor(s2a[ot], 16); s2a[ot] += __shfl_xor(s2a[ot], 32);
            }
            if (quad == 0) {
#pragma unroll
                for (int ot = 0; ot < 4; ot++) {
                    atomicAdd(&red[ot * 16 + l16], s1a[ot]);
                    atomicAdd(&red[64 + ot * 16 + l16], s2a[ot]);
                }
            }
            __syncthreads();
            if (tid < 128) atomicAdd(&stats[128 + tid], red[tid]);
        }
    }
}

// --------------------------- BN1 + lrelu + pooling -> fp32 out -------------
__global__ __launch_bounds__(256) void k_final(const u16* __restrict__ op,
                                               const float* __restrict__ stats,
                                               const u16* __restrict__ pc,
                                               float* __restrict__ out) {
    const int o = blockIdx.x * 256 + threadIdx.x;
    const int f = o & 63, n = (o >> 6) & 255, b = o >> 14;
    const float inv = 1.f / 131072.f;
    const float mu = stats[128 + f] * inv;
    const float var = fmaxf(stats[192 + f] * inv - mu * mu, 0.f);
    const float rs = rsqrtf(var + 1e-5f);
    const float scale = rs * bf2f(pc[B1W_O + f]);
    const float shift = bf2f(pc[B1B_O + f]) - mu * scale;
    float acc = 0.f;
    for (int l = 0; l < 16; l++) {
        const size_t pb = (size_t)(b * 16 + l) * N1 * FD;
#pragma unroll
        for (int m = 0; m < 2; m++) {
            float v = bf2f(op[pb + (size_t)(m * 256 + n) * 64 + f]);
            v = v * scale + shift;
            acc += (v > 0.f ? v : 0.01f * v);
        }
    }
    out[o] = acc * (1.f / 32.f);
}

// ---------------------------------------------------------------------------
extern "C" void kernel_launch(void* const* d_in, const int* in_sizes, int n_in,
                              void* d_out, int out_size, void* d_ws, size_t ws_size,
                              hipStream_t stream) {
    char* ws = (char*)d_ws;
    size_t off = 0;
    auto alloc = [&](size_t bytes) { void* pp = ws + off; off += (bytes + 255) & ~(size_t)255; return pp; };
    u16* y = (u16*)alloc((size_t)Y_ELEMS * 2);
    u16* opre = (u16*)alloc((size_t)NB * N1 * FD * 2);
    u16* pc = (u16*)alloc(P_TOT * 2);
    float* stats = (float*)alloc(256 * 4);
    int* flag = (int*)alloc(256);
    float* out = (float*)d_out;

    k_prep<<<50, 256, 0, stream>>>(d_in[1], d_in[2], d_in[3], d_in[4], d_in[5],
                                   d_in[6], d_in[7], d_in[8], d_in[9], d_in[10],
                                   flag, pc, stats);
    k_y<<<BSZ * SNUM, 256, 0, stream>>>(d_in[0], flag, pc, y, stats);
    k_mega<<<NB, 512, LDS_BYTES, stream>>>(y, stats, pc, opre);
    k_final<<<1024, 256, 0, stream>>>(opre, stats, pc, out);
}